// Round 15
// baseline (167.003 us; speedup 1.0000x reference)
//
#include <hip/hip_runtime.h>

#define N_NODES 50000
#define N_EDGES 800000
#define D_IN    256
#define D_OUT   128
#define ELL_S   64                         // ELL stride; P(deg>=64)~1e-18 for Poisson(16)
#define PART_BLKS 391                      // D1: partition blocks (bids 0..390)
#define PACK_BLKS 16                       // D1: W-pack blocks (bids 391..406)
#define GEMM_BLKS 391                      // D2: GEMM blocks (bids 0..390)
#define NBINS   196                        // bins of 256 dsts: ceil(50000/256); D2 bids 391..586
#define EPB     2048                       // edges per partition block (8/thread)
#define CAPB    40                         // per-(block,bin) cap = 10 uint4; P(>40)~1e-13/cell

typedef __attribute__((ext_vector_type(8))) short short8;
typedef __attribute__((ext_vector_type(4))) float floatx4;

__device__ __forceinline__ unsigned short f2bf(float f) {
    unsigned int u = __float_as_uint(f);
    unsigned int r = (u + 0x7fffu + ((u >> 16) & 1u)) >> 16;   // RNE
    return (unsigned short)r;
}
__device__ __forceinline__ unsigned int pack2(float a, float b) {
    return (unsigned int)f2bf(a) | ((unsigned int)f2bf(b) << 16);
}
__device__ __forceinline__ float bfl(unsigned int u) { return __uint_as_float(u << 16); }
__device__ __forceinline__ float bfh(unsigned int u) { return __uint_as_float(u & 0xffff0000u); }

// ---------------------------------------------------------------------------
// D1: partition (bids 0..390) || W fragment pack (bids 391..406).
// Unchanged (validated r10-r14).
// ---------------------------------------------------------------------------
__global__ __launch_bounds__(256) void part_kernel(const void* __restrict__ ei,
                                                   const float* __restrict__ W,
                                                   unsigned short* __restrict__ bfrag,
                                                   int* __restrict__ packed,
                                                   int* __restrict__ blkBinCnt) {
    __shared__ int hist[NBINS];
    __shared__ int found32;
    const int bid = blockIdx.x;
    const int tid = threadIdx.x;

    if (bid >= PART_BLKS) {
        // ---- W fragment pack ----
        int g = (bid - PART_BLKS) * 256 + tid;   // 0..4095
        int gl = g & 63;
        int kc = (g >> 6) & 7;
        int ct = g >> 9;
        int n  = ct * 16 + (gl & 15);
        int kb = kc * 32 + ((gl >> 4) & 3) * 8;
        unsigned int p[4];
#pragma unroll
        for (int jj = 0; jj < 4; jj++) {
            float a = W[(size_t)(kb + 2 * jj + 0) * D_OUT + n];
            float b = W[(size_t)(kb + 2 * jj + 1) * D_OUT + n];
            p[jj] = pack2(a, b);
        }
        *(uint4*)&bfrag[(size_t)g * 8] = make_uint4(p[0], p[1], p[2], p[3]);
        return;
    }

    // ---- partition, zero global atomics ----
    int sb = bid;
    if (tid < NBINS) hist[tid] = 0;
    if (tid == 0) found32 = 0;
    __syncthreads();
    {   // per-block edge-dtype detect (int32 input -> odd dwords are src ids)
        const unsigned int* e32 = (const unsigned int*)ei;
        if (e32[2 * tid + 1] != 0u) atomicOr(&found32, 1);   // LDS atomic
    }
    __syncthreads();
    int is64 = !found32;

    int ebase = sb * EPB + tid;
    int sv[8], bn[8], dl[8], lr[8];
    if (is64) {
        const long long* p = (const long long*)ei;
#pragma unroll
        for (int i = 0; i < 8; i++) {
            int e = ebase + i * 256;
            if (e < N_EDGES) {
                sv[i] = (int)p[e];
                int d = (int)p[N_EDGES + e];
                bn[i] = d >> 8; dl[i] = d & 255;
            } else bn[i] = -1;
        }
    } else {
        const int* p = (const int*)ei;
#pragma unroll
        for (int i = 0; i < 8; i++) {
            int e = ebase + i * 256;
            if (e < N_EDGES) {
                sv[i] = p[e];
                int d = p[N_EDGES + e];
                bn[i] = d >> 8; dl[i] = d & 255;
            } else bn[i] = -1;
        }
    }
#pragma unroll
    for (int i = 0; i < 8; i++)
        if (bn[i] >= 0) lr[i] = atomicAdd(&hist[bn[i]], 1);   // LDS atomic rank
#pragma unroll
    for (int i = 0; i < 8; i++) {
        if (bn[i] >= 0 && lr[i] < CAPB)
            packed[((size_t)sb * NBINS + bn[i]) * CAPB + lr[i]] = sv[i] | (dl[i] << 24);
    }
    __syncthreads();
    for (int t = tid; t < NBINS; t += 256)
        blkBinCnt[sb * NBINS + t] = hist[t];                  // fully written, no zeroing
}

// ---------------------------------------------------------------------------
// D2: GEMM (bids 0..390) || single-pass ELL build (bids 391..586).
//
// ROUND-15: GEMM arm gets double-buffered As + T14 stage-split. The old
// loop paid 2 barrier-drains per k0-iter (16/block), each a full
// vmcnt(0)+lgkmcnt(0) drain, and staging loads serialized behind compute.
// Now: issue next-tile f32 loads -> MFMA current buffer -> pack+ds_write
// next buffer -> ONE barrier (9/block). Writes at iter k target the buffer
// read at iter k-1 (fenced by that iter's barrier) -> race-free. HBM load
// latency hides under ds_read+MFMA (waitcnt lands after the MFMA cluster).
// LDS 2x10KB + overlay = 20.5KB (no occupancy cliff). ELL arm unchanged
// from r14 (validated).
// ---------------------------------------------------------------------------
__global__ __launch_bounds__(256) void fused_kernel(const float* __restrict__ x,
                                                    const unsigned short* __restrict__ bf,
                                                    unsigned short* __restrict__ h,
                                                    const int* __restrict__ packed,
                                                    const int* __restrict__ blkBinCnt,
                                                    int* __restrict__ cnt,
                                                    int* __restrict__ bucket) {
    __shared__ __align__(16) char smem[20480];               // overlay: As[2] | c256
    unsigned short (*As)[128][40] = (unsigned short(*)[128][40])smem;  // 2 x 10240 B
    unsigned int* c256 = (unsigned int*)smem;                // [256] = 1024 B
    int tid = threadIdx.x;

    if (blockIdx.x >= GEMM_BLKS) {
        // ---- ELL build for bin j (single pass, batched predicated loads) ----
        int j = blockIdx.x - GEMM_BLKS;
        c256[tid] = 0;
        __syncthreads();
        for (int sb = tid; sb < PART_BLKS; sb += 256) {
            int c = blkBinCnt[sb * NBINS + j];
            if (c > CAPB) c = CAPB;
            const uint4* seg4 = (const uint4*)(packed + ((size_t)sb * NBINS + j) * CAPB);
            uint4 rv[10];
#pragma unroll
            for (int q = 0; q < 10; q++)
                if (q * 4 < c) rv[q] = seg4[q];               // independent, one latency
#pragma unroll
            for (int q = 0; q < 10; q++) {
                unsigned int rr[4] = {rv[q].x, rv[q].y, rv[q].z, rv[q].w};
#pragma unroll
                for (int e = 0; e < 4; e++) {
                    if (q * 4 + e < c) {
                        unsigned int rec = rr[e];
                        int dl = rec >> 24;
                        int s  = rec & 0xFFFFFF;
                        unsigned int pos = atomicAdd(&c256[dl], 1u);   // LDS atomic
                        if (pos < ELL_S) bucket[(size_t)((j << 8) + dl) * ELL_S + pos] = s;
                    }
                }
            }
        }
        __syncthreads();
        int d = (j << 8) + tid;
        if (d < N_NODES) cnt[d] = (int)c256[tid];             // counter = true degree
        return;
    }

    // ---- GEMM: double-buffered As, 1 barrier/iter, T14 stage split ----
    int row0 = blockIdx.x * 128;
    int w    = tid >> 6;
    int lane = tid & 63;
    int quad = lane >> 4;
    int l15  = lane & 15;

    floatx4 acc[2][8];
#pragma unroll
    for (int i = 0; i < 2; i++)
#pragma unroll
        for (int j = 0; j < 8; j++) acc[i][j] = (floatx4){0.f, 0.f, 0.f, 0.f};

    int srow  = tid >> 1;            // 0..127
    int shalf = (tid & 1) * 16;
    const float* xrow = x + (size_t)(row0 + srow) * D_IN;
    bool svalid = (row0 + srow) < N_NODES;

    // prologue: stage tile 0 into buffer 0
    {
        uint4 p0 = make_uint4(0, 0, 0, 0), p1 = make_uint4(0, 0, 0, 0);
        if (svalid) {
            const float* src = xrow + shalf;
            float4 f0 = *(const float4*)(src + 0);
            float4 f1 = *(const float4*)(src + 4);
            float4 f2 = *(const float4*)(src + 8);
            float4 f3 = *(const float4*)(src + 12);
            p0 = make_uint4(pack2(f0.x, f0.y), pack2(f0.z, f0.w),
                            pack2(f1.x, f1.y), pack2(f1.z, f1.w));
            p1 = make_uint4(pack2(f2.x, f2.y), pack2(f2.z, f2.w),
                            pack2(f3.x, f3.y), pack2(f3.z, f3.w));
        }
        *(uint4*)&As[0][srow][shalf + 0] = p0;
        *(uint4*)&As[0][srow][shalf + 8] = p1;
    }
    __syncthreads();

#pragma unroll
    for (int k0 = 0; k0 < 8; k0++) {         // K-chunk index (K = k0*32)
        int cur = k0 & 1;
        // T14: issue next tile's global loads BEFORE compute (latency hides
        // under ds_read+MFMA; the waitcnt lands at the pack below)
        float4 f0, f1, f2, f3;
        bool stage = (k0 < 7) && svalid;
        if (stage) {
            const float* src = xrow + (k0 + 1) * 32 + shalf;
            f0 = *(const float4*)(src + 0);
            f1 = *(const float4*)(src + 4);
            f2 = *(const float4*)(src + 8);
            f3 = *(const float4*)(src + 12);
        }

        // compute from As[cur]
        short8 a0 = *(const short8*)&As[cur][w * 32 + l15][quad * 8];
        short8 a1 = *(const short8*)&As[cur][w * 32 + 16 + l15][quad * 8];
#pragma unroll
        for (int ct = 0; ct < 8; ct++) {
            short8 b = *(const short8*)&bf[(size_t)(((ct * 8 + k0) * 64 + lane)) * 8];
            acc[0][ct] = __builtin_amdgcn_mfma_f32_16x16x32_bf16(a0, b, acc[0][ct], 0, 0, 0);
            acc[1][ct] = __builtin_amdgcn_mfma_f32_16x16x32_bf16(a1, b, acc[1][ct], 0, 0, 0);
        }

        // pack + write next tile into the other buffer (read last iter,
        // already fenced by the previous barrier -> no WAR race)
        if (k0 < 7) {
            uint4 p0 = make_uint4(0, 0, 0, 0), p1 = make_uint4(0, 0, 0, 0);
            if (stage) {
                p0 = make_uint4(pack2(f0.x, f0.y), pack2(f0.z, f0.w),
                                pack2(f1.x, f1.y), pack2(f1.z, f1.w));
                p1 = make_uint4(pack2(f2.x, f2.y), pack2(f2.z, f2.w),
                                pack2(f3.x, f3.y), pack2(f3.z, f3.w));
            }
            *(uint4*)&As[cur ^ 1][srow][shalf + 0] = p0;
            *(uint4*)&As[cur ^ 1][srow][shalf + 8] = p1;
        }
        __syncthreads();
    }

#pragma unroll
    for (int rt = 0; rt < 2; rt++) {
        int grow0 = row0 + w * 32 + rt * 16 + quad * 4;
#pragma unroll
        for (int r = 0; r < 4; r++) {
            int grow = grow0 + r;
            if (grow < N_NODES) {
#pragma unroll
                for (int ct = 0; ct < 8; ct++) {
                    h[(size_t)grow * D_OUT + ct * 16 + l15] = f2bf(acc[rt][ct][r]);
                }
            }
        }
    }
}

// ---------------------------------------------------------------------------
// D3 gather (unchanged from rounds 10-14): 4 dst/wave, 16 lanes/node, 8 bf16
// ch/lane, per-group exact bounds. At its structural floor: ~102MB h traffic
// (each XCD reads h once) + bucket/cnt at the ~10.5 B/cyc/CU random-granule
// wall (invariant across r7/r8/r10/r13/r14 structural variants).
// ---------------------------------------------------------------------------
#define GACC(U, F)                                      \
    a0 += bfl(U.x) * (F); a1 += bfh(U.x) * (F);         \
    a2 += bfl(U.y) * (F); a3 += bfh(U.y) * (F);         \
    a4 += bfl(U.z) * (F); a5 += bfh(U.z) * (F);         \
    a6 += bfl(U.w) * (F); a7 += bfh(U.w) * (F);

#define GBODY(SS, WW, KB)                                                         \
    {                                                                             \
        int lim = n - (KB);                                                       \
        if (lim > 16) lim = 16;                                                   \
        lim = (lim + 3) & ~3;                                                     \
        for (int k = 0; k < lim; k += 4) {                                        \
            int   s0 = __shfl((SS), gk + k + 0), s1 = __shfl((SS), gk + k + 1);   \
            int   s2 = __shfl((SS), gk + k + 2), s3 = __shfl((SS), gk + k + 3);   \
            float f0 = __shfl((WW), gk + k + 0), f1 = __shfl((WW), gk + k + 1);   \
            float f2 = __shfl((WW), gk + k + 2), f3 = __shfl((WW), gk + k + 3);   \
            uint4 u0 = *(const uint4*)(h + (size_t)s0 * D_OUT + co);              \
            uint4 u1 = *(const uint4*)(h + (size_t)s1 * D_OUT + co);              \
            uint4 u2 = *(const uint4*)(h + (size_t)s2 * D_OUT + co);              \
            uint4 u3 = *(const uint4*)(h + (size_t)s3 * D_OUT + co);              \
            GACC(u0, f0); GACC(u1, f1); GACC(u2, f2); GACC(u3, f3);               \
        }                                                                         \
    }

__global__ __launch_bounds__(256) void gather_kernel(
    const unsigned short* __restrict__ h, const int* __restrict__ cnt,
    const int* __restrict__ bucket, const float* __restrict__ bias,
    const float* __restrict__ pa, float* __restrict__ out) {
    int wave = (int)((blockIdx.x * blockDim.x + threadIdx.x) >> 6);
    int lane = threadIdx.x & 63;
    int g  = lane >> 4;            // node slot within wave (0..3)
    int l  = lane & 15;            // lane within node group
    int gk = g << 4;
    int d  = wave * 4 + g;         // N_NODES % 4 == 0 -> always valid
    if (wave >= N_NODES / 4) return;

    int nraw = cnt[d];
    int n = nraw < ELL_S ? nraw : ELL_S;
    if (n < 0) n = 0;
    float di = rsqrtf((float)(nraw + 1));

    int co = l * 8;                // channel offset: 8 channels/lane (16 B)

    // self-loop: h[d] * di^2
    uint4 us = *(const uint4*)(h + (size_t)d * D_OUT + co);
    float sl = di * di;
    float a0 = bfl(us.x) * sl, a1 = bfh(us.x) * sl;
    float a2 = bfl(us.y) * sl, a3 = bfh(us.y) * sl;
    float a4 = bfl(us.z) * sl, a5 = bfh(us.z) * sl;
    float a6 = bfl(us.w) * sl, a7 = bfh(us.w) * sl;

    // preload ELL row: 4 chunks of 16 slots; invalid slots get (s=0, w=0)
    int db = d * ELL_S;
    int   s0v = 0,   s1v = 0,   s2v = 0,   s3v = 0;
    float w0v = 0.f, w1v = 0.f, w2v = 0.f, w3v = 0.f;
    if (l      < n) { s0v = bucket[db + l];      w0v = rsqrtf((float)(cnt[s0v] + 1)) * di; }
    if (l + 16 < n) { s1v = bucket[db + l + 16]; w1v = rsqrtf((float)(cnt[s1v] + 1)) * di; }
    if (l + 32 < n) { s2v = bucket[db + l + 32]; w2v = rsqrtf((float)(cnt[s2v] + 1)) * di; }
    if (l + 48 < n) { s3v = bucket[db + l + 48]; w3v = rsqrtf((float)(cnt[s3v] + 1)) * di; }

    // per-group exact section bounds (divergent across the 4 groups; masked
    // groups issue no memory requests)
    if (n > 0)  GBODY(s0v, w0v, 0)
    if (n > 16) GBODY(s1v, w1v, 16)
    if (n > 32) GBODY(s2v, w2v, 32)
    if (n > 48) GBODY(s3v, w3v, 48)

    int c = l * 8;
    float4 b0 = *(const float4*)&bias[c];
    float4 b1 = *(const float4*)&bias[c + 4];
    float4 p0 = *(const float4*)&pa[c];
    float4 p1 = *(const float4*)&pa[c + 4];
    float4 o0, o1;
    o0.x = a0 + b0.x; o0.y = a1 + b0.y; o0.z = a2 + b0.z; o0.w = a3 + b0.w;
    o1.x = a4 + b1.x; o1.y = a5 + b1.y; o1.z = a6 + b1.z; o1.w = a7 + b1.w;
    o0.x = o0.x > 0.f ? o0.x : p0.x * o0.x;
    o0.y = o0.y > 0.f ? o0.y : p0.y * o0.y;
    o0.z = o0.z > 0.f ? o0.z : p0.z * o0.z;
    o0.w = o0.w > 0.f ? o0.w : p0.w * o0.w;
    o1.x = o1.x > 0.f ? o1.x : p1.x * o1.x;
    o1.y = o1.y > 0.f ? o1.y : p1.y * o1.y;
    o1.z = o1.z > 0.f ? o1.z : p1.z * o1.z;
    o1.w = o1.w > 0.f ? o1.w : p1.w * o1.w;
    *(float4*)&out[(size_t)d * D_OUT + c]     = o0;
    *(float4*)&out[(size_t)d * D_OUT + c + 4] = o1;
}

extern "C" void kernel_launch(void* const* d_in, const int* in_sizes, int n_in,
                              void* d_out, int out_size, void* d_ws, size_t ws_size,
                              hipStream_t stream) {
    const float* x  = (const float*)d_in[0];
    const void*  ei = d_in[1];
    const float* W  = (const float*)d_in[2];
    const float* b  = (const float*)d_in[3];
    const float* pa = (const float*)d_in[4];
    float* out = (float*)d_out;

    char* w = (char*)d_ws;
    unsigned short* bfrag = (unsigned short*)w; w += 8 * 8 * 64 * 8 * 2;   // 64 KB
    int*   packed = (int*)w;    w += (size_t)PART_BLKS * NBINS * CAPB * 4; // 12.3 MB
    int*   bbc    = (int*)w;    w += (size_t)PART_BLKS * NBINS * 4;        // 307 KB
    int*   cnt    = (int*)w;    w += (size_t)NBINS * 256 * 4;              // 200 KB
    int*   bucket = (int*)w;    w += (size_t)N_NODES * ELL_S * 4;          // 12.8 MB
    unsigned short* h = (unsigned short*)w; w += (size_t)N_NODES * D_OUT * 2;

    part_kernel<<<PART_BLKS + PACK_BLKS, 256, 0, stream>>>(ei, W, bfrag, packed, bbc);
    fused_kernel<<<GEMM_BLKS + NBINS, 256, 0, stream>>>(x, bfrag, h, packed, bbc, cnt, bucket);
    gather_kernel<<<(N_NODES / 4 * 64 + 255) / 256, 256, 0, stream>>>(h, cnt, bucket, b, pa, out);
}